// Round 10
// baseline (1528.502 us; speedup 1.0000x reference)
//
#include <hip/hip_runtime.h>
#include <hip/hip_bf16.h>

// Problem constants: B=16, S=256, V=32000, E=256, H=8, L=2, FFN=1024, NC=4, DK=32, NQ=256

typedef __attribute__((ext_vector_type(8))) short bf8v;   // 8 bf16 in 4 VGPRs
typedef __attribute__((ext_vector_type(4))) float f4v;    // MFMA accumulator
#define MFMA16 __builtin_amdgcn_mfma_f32_16x16x32_bf16

__device__ __forceinline__ unsigned short f2bf(float f) {
  unsigned u = __builtin_bit_cast(unsigned, f);
  u += 0x7fffu + ((u >> 16) & 1u);
  return (unsigned short)(u >> 16);
}
__device__ __forceinline__ float rcp_f(float x) { return __builtin_amdgcn_rcpf(x); }
__device__ __forceinline__ float sigm(float x) { return rcp_f(1.f + __expf(-x)); }
__device__ __forceinline__ float tanh_f(float x) { return 1.f - 2.f * rcp_f(__expf(2.f * x) + 1.f); }

// v_dot2_f32_bf16: acc += a.x*b.x + a.y*b.y  (packed bf16 pairs in uint)
#define DOT2BF(acc, a, b) \
  asm("v_dot2_f32_bf16 %0, %1, %2, %0" : "+v"(acc) : "v"(a), "v"(b))

// ---------------- embedding gather -> bf16 ----------------
__global__ void embed_kernel(const int* __restrict__ x, const float* __restrict__ tab,
                             unsigned short* __restrict__ eb) {
  int tok = blockIdx.x, tid = threadIdx.x;
  eb[tok * 256 + tid] = f2bf(tab[x[tok] * 256 + tid]);
}

// ---- transpose to bf16: W [K][N] f32 -> T[n][k] bf16 ; blockIdx.z batches slices ----
__global__ void pack_bt(const float* __restrict__ W, int K, int N,
                        unsigned short* __restrict__ Th, long wz, long tz) {
  __shared__ float tile[64][65];
  W += (long)blockIdx.z * wz;
  Th += (long)blockIdx.z * tz;
  int n0 = blockIdx.x * 64, k0 = blockIdx.y * 64;
  int tid = threadIdx.x, tx = tid & 63, ty = tid >> 6;
  for (int r = ty; r < 64; r += 4) tile[r][tx] = W[(k0 + r) * N + n0 + tx];
  __syncthreads();
  for (int r = ty; r < 64; r += 4) {
    Th[(n0 + r) * K + k0 + tx] = f2bf(tile[tx][r]);  // = W[k0+tx][n0+r]
  }
}

// ---- pack h-part of gates 0..2 as bf16 d-pairs; half-split (s=0..1, 128 d each) ----
// uint o = ((gs*16 + i4)*256 + q)*4 + c ; gs=gi*2+s, pair i=i4*4+c, d=s*128+2i
__global__ void pack_wreg_kernel(const float* __restrict__ lstmW, unsigned* __restrict__ Wreg) {
  int o = blockIdx.x * 256 + threadIdx.x;  // < 98304
  int c = o & 3;
  int q = (o >> 2) & 255;
  int i4 = (o >> 10) & 15;
  int gs = o >> 14;  // 0..5
  int gi = gs >> 1, s = gs & 1;
  int i = i4 * 4 + c;
  int d = s * 128 + 2 * i;
  unsigned lo = f2bf(lstmW[(gi * 512 + 256 + d) * 256 + q]);
  unsigned hi = f2bf(lstmW[(gi * 512 + 256 + d + 1) * 256 + q]);
  Wreg[o] = lo | (hi << 16);
}

// ---- pack h-part of gate 3 as bf16 d-pairs for LDS ----
__global__ void pack_wl_kernel(const float* __restrict__ lstmW, unsigned* __restrict__ WLg) {
  int o = blockIdx.x * 256 + threadIdx.x;  // < 32768
  int c = o & 3;
  int q = (o >> 2) & 255;
  int p4 = o >> 10;  // 0..31
  int d = 2 * (p4 * 4 + c);
  unsigned lo = f2bf(lstmW[(3 * 512 + 256 + d) * 256 + q]);
  unsigned hi = f2bf(lstmW[(3 * 512 + 256 + d + 1) * 256 + q]);
  WLg[o] = lo | (hi << 16);
}

// ---------------- MFMA GEMM 128x128: C = A*B + bias ----------------
__global__ void __launch_bounds__(256) gemm_mfma(const unsigned short* __restrict__ A,
                                                 const unsigned short* __restrict__ B,
                                                 const float* __restrict__ bias,
                                                 float* __restrict__ Cf,
                                                 unsigned short* __restrict__ Cb,
                                                 int M, int N, int K, int mode) {
  __shared__ unsigned short As[128 * 40];
  __shared__ unsigned short Bs[128 * 40];

  const int tid = threadIdx.x;
  const int lane = tid & 63;
  const int wid = tid >> 6;
  const int wr = wid >> 1, wc = wid & 1;
  const int bm = blockIdx.y * 128, bn = blockIdx.x * 128;

  const int srow = tid >> 2;
  const int scol = (tid & 3) * 8;

  f4v acc[4][4] = {};

  for (int kt = 0; kt < K; kt += 32) {
#pragma unroll
    for (int p = 0; p < 2; ++p) {
      int r = srow + p * 64;
      *(uint4*)(&As[r * 40 + scol]) = *(const uint4*)(&A[(bm + r) * K + kt + scol]);
      *(uint4*)(&Bs[r * 40 + scol]) = *(const uint4*)(&B[(bn + r) * K + kt + scol]);
    }
    __syncthreads();

    bf8v a[4], b[4];
    const int kq = (lane >> 4) * 8;
#pragma unroll
    for (int f = 0; f < 4; ++f) {
      a[f] = *(const bf8v*)(&As[(wr * 64 + f * 16 + (lane & 15)) * 40 + kq]);
      b[f] = *(const bf8v*)(&Bs[(wc * 64 + f * 16 + (lane & 15)) * 40 + kq]);
    }
#pragma unroll
    for (int fm = 0; fm < 4; ++fm)
#pragma unroll
      for (int fn = 0; fn < 4; ++fn)
        acc[fm][fn] = MFMA16(a[fm], b[fn], acc[fm][fn], 0, 0, 0);
    __syncthreads();
  }

#pragma unroll
  for (int fm = 0; fm < 4; ++fm)
#pragma unroll
    for (int fn = 0; fn < 4; ++fn) {
      int c = bn + wc * 64 + fn * 16 + (lane & 15);
      int r0 = bm + wr * 64 + fm * 16 + ((lane >> 4) << 2);
      float bv = bias[c];
#pragma unroll
      for (int j = 0; j < 4; ++j) {
        float v = acc[fm][fn][j] + bv;
        if (mode == 1) {
          Cb[(r0 + j) * N + c] = f2bf(fmaxf(v, 0.f));
        } else {
          Cf[(r0 + j) * N + c] = v;
        }
      }
    }
}

// ---------------- MFMA GEMM 64x64 tile (for N=256: 4x the blocks of 128-tile) ----------------
__global__ void __launch_bounds__(256) gemm64(const unsigned short* __restrict__ A,
                                              const unsigned short* __restrict__ B,
                                              const float* __restrict__ bias,
                                              float* __restrict__ Cf,
                                              int M, int N, int K) {
  __shared__ unsigned short As[64 * 40];
  __shared__ unsigned short Bs[64 * 40];

  const int tid = threadIdx.x;
  const int lane = tid & 63;
  const int wid = tid >> 6;          // wave owns M-rows [wid*16, wid*16+16)
  const int bm = blockIdx.y * 64, bn = blockIdx.x * 64;
  const int srow = tid >> 2;         // 0..63
  const int scol = (tid & 3) * 8;

  f4v acc[4] = {};

  for (int kt = 0; kt < K; kt += 32) {
    *(uint4*)(&As[srow * 40 + scol]) = *(const uint4*)(&A[(bm + srow) * K + kt + scol]);
    *(uint4*)(&Bs[srow * 40 + scol]) = *(const uint4*)(&B[(bn + srow) * K + kt + scol]);
    __syncthreads();

    const int kq = (lane >> 4) * 8;
    bf8v a = *(const bf8v*)(&As[(wid * 16 + (lane & 15)) * 40 + kq]);
#pragma unroll
    for (int f = 0; f < 4; ++f) {
      bf8v b = *(const bf8v*)(&Bs[(f * 16 + (lane & 15)) * 40 + kq]);
      acc[f] = MFMA16(a, b, acc[f], 0, 0, 0);
    }
    __syncthreads();
  }

#pragma unroll
  for (int f = 0; f < 4; ++f) {
    int c = bn + f * 16 + (lane & 15);
    int r0 = bm + wid * 16 + ((lane >> 4) << 2);
    float bv = bias[c];
#pragma unroll
    for (int j = 0; j < 4; ++j) {
      Cf[(r0 + j) * N + c] = acc[f][j] + bv;
    }
  }
}

// ---------------- QLSTM: 16 blocks (1/batch); gates 0..2 weights in AGPRs ----------------
// 512 threads: q=t&255, s=t>>8 (d-half). 192 packed bf16-pair dwords per thread live in
// AGPRs via asm "a"-class constraints (asm volatile defs can't be rematerialized/sunk);
// gate 3 [256][256] bf16 in LDS. Zero per-step global weight traffic.
#define DECLA4(gi, i4) \
  unsigned ag##gi##_##i4##_0, ag##gi##_##i4##_1, ag##gi##_##i4##_2, ag##gi##_##i4##_3;
#define DECLG(gi) \
  DECLA4(gi, 0) DECLA4(gi, 1) DECLA4(gi, 2) DECLA4(gi, 3) \
  DECLA4(gi, 4) DECLA4(gi, 5) DECLA4(gi, 6) DECLA4(gi, 7) \
  DECLA4(gi, 8) DECLA4(gi, 9) DECLA4(gi, 10) DECLA4(gi, 11) \
  DECLA4(gi, 12) DECLA4(gi, 13) DECLA4(gi, 14) DECLA4(gi, 15)

#define LOADA4(gi, i4) { \
  uint4 tw = Wreg4[(((gi) * 2 + s) * 16 + (i4)) * 256 + q]; \
  asm volatile("v_accvgpr_write_b32 %0, %1" : "=a"(ag##gi##_##i4##_0) : "v"(tw.x)); \
  asm volatile("v_accvgpr_write_b32 %0, %1" : "=a"(ag##gi##_##i4##_1) : "v"(tw.y)); \
  asm volatile("v_accvgpr_write_b32 %0, %1" : "=a"(ag##gi##_##i4##_2) : "v"(tw.z)); \
  asm volatile("v_accvgpr_write_b32 %0, %1" : "=a"(ag##gi##_##i4##_3) : "v"(tw.w)); }
#define LOADG(gi) \
  LOADA4(gi, 0) LOADA4(gi, 1) LOADA4(gi, 2) LOADA4(gi, 3) \
  LOADA4(gi, 4) LOADA4(gi, 5) LOADA4(gi, 6) LOADA4(gi, 7) \
  LOADA4(gi, 8) LOADA4(gi, 9) LOADA4(gi, 10) LOADA4(gi, 11) \
  LOADA4(gi, 12) LOADA4(gi, 13) LOADA4(gi, 14) LOADA4(gi, 15)

// read AGPR -> temp VGPR, then dot2 (both plain VALU; HW interlocks cover the dep)
#define DOTA1(acc, areg, hw) { unsigned t_; \
  asm("v_accvgpr_read_b32 %1, %2\n\tv_dot2_f32_bf16 %0, %1, %3, %0" \
      : "+v"(acc), "=&v"(t_) : "a"(areg), "v"(hw)); }
#define DOTA(acc, gi, i4, hh) \
  DOTA1(acc, ag##gi##_##i4##_0, (hh).x) \
  DOTA1(acc, ag##gi##_##i4##_1, (hh).y) \
  DOTA1(acc, ag##gi##_##i4##_2, (hh).z) \
  DOTA1(acc, ag##gi##_##i4##_3, (hh).w)

#define CHUNKA(i4) { \
  uint4 hh = hp4[(s << 4) + (i4)]; \
  uint4 w3 = WL4[((s << 4) + (i4)) * 256 + q]; \
  DOTA(a0, 0, i4, hh) \
  DOTA(a1, 1, i4, hh) \
  DOTA(a2, 2, i4, hh) \
  DOT2BF(a3, w3.x, hh.x); DOT2BF(a3, w3.y, hh.y); \
  DOT2BF(a3, w3.z, hh.z); DOT2BF(a3, w3.w, hh.w); }

__global__ void
__attribute__((amdgpu_flat_work_group_size(512, 512), amdgpu_waves_per_eu(2, 2)))
lstm_kernel(const unsigned* __restrict__ Wreg,
            const unsigned* __restrict__ WLg,
            const float* __restrict__ lstmTh,
            const float* __restrict__ xw,
            float* __restrict__ hb) {
  extern __shared__ char smem[];
  unsigned* WL = (unsigned*)smem;               // [32][256] uint4 rows (131072 B) gate 3
  float* part = (float*)(smem + 131072);        // [8][256]  (g*2+s, q)
  float* qv = part + 2048;                      // [1024]  segment-scan values, gate-major
  float* wtot = qv + 1024;                      // [16]  (wave, slot)
  unsigned* hp = (unsigned*)(wtot + 16);        // [128] packed bf16 h pairs

  const int t = threadIdx.x;
  const int b = blockIdx.x;
  const int q = t & 255;
  const int s = t >> 8;
  const int lane = t & 63;
  const int w = t >> 6;  // wave 0..7

  {
    const uint4* src = (const uint4*)WLg;
    uint4* dst = (uint4*)WL;
    for (int j = t; j < 8192; j += 512) dst[j] = src[j];
  }
  const uint4* Wreg4 = (const uint4*)Wreg;
  DECLG(0) DECLG(1) DECLG(2)
  LOADG(0) LOADG(1) LOADG(2)
  const float thA = lstmTh[t];          // gate s, col q
  const float thB = lstmTh[512 + t];    // gate s+2, col q
  float cx = 0.f;                       // valid for t<256 (q-owner)
  if (t < 128) hp[t] = 0u;
  __syncthreads();

  const int xbase = (b << 8) * 1024;
  const uint4* WL4 = (const uint4*)WL;
  const uint4* hp4 = (const uint4*)hp;

  float xa = xw[xbase + t];
  float xb = xw[xbase + 512 + t];
  // PE constants for this thread's output column q (t<256)
  const float pediv = __expf((float)(q >> 1) * -0.07195578415622253f);

  for (int st = 0; st < 256; ++st) {
    int nx = (st < 255) ? st + 1 : 255;
    float xa_n = xw[xbase + nx * 1024 + t];
    float xb_n = xw[xbase + nx * 1024 + 512 + t];

    // ---- GEMV half-dots: 4 gates, 128 d each; gates 0..2 from AGPR, gate 3 LDS ----
    float a0 = 0.f, a1 = 0.f, a2 = 0.f, a3 = 0.f;
    CHUNKA(0) CHUNKA(1) CHUNKA(2) CHUNKA(3)
    CHUNKA(4) CHUNKA(5) CHUNKA(6) CHUNKA(7)
    CHUNKA(8) CHUNKA(9) CHUNKA(10) CHUNKA(11)
    CHUNKA(12) CHUNKA(13) CHUNKA(14) CHUNKA(15)
    part[(0 * 2 + s) * 256 + q] = a0;
    part[(1 * 2 + s) * 256 + q] = a1;
    part[(2 * 2 + s) * 256 + q] = a2;
    part[(3 * 2 + s) * 256 + q] = a3;
    __syncthreads();  // bar1: partials ready

    // ---- finalize z; cos; segment scan (wave = one 64-col segment) ----
    int gA = s, gB = s + 2;
    float zA = part[(gA * 2 + 0) * 256 + q] + part[(gA * 2 + 1) * 256 + q] + xa + thA;
    float zB = part[(gB * 2 + 0) * 256 + q] + part[(gB * 2 + 1) * 256 + q] + xb + thB;
    float vA = __cosf(zA);
    float vB = __cosf(zB);
#pragma unroll
    for (int off = 1; off < 64; off <<= 1) {
      float oA = __shfl_up(vA, off, 64);
      float oB = __shfl_up(vB, off, 64);
      if (lane >= off) { vA *= oA; vB *= oB; }
    }
    if (lane == 63) { wtot[w * 2] = vA; wtot[w * 2 + 1] = vB; }
    qv[s * 256 + q] = vA;        // gate s     (segment-local scan)
    qv[512 + s * 256 + q] = vB;  // gate s+2
    __syncthreads();  // bar2: qv + wtot ready

    // ---- combine (threads 0..255 own column q); apply segment prefixes here ----
    if (t < 256) {
      int j = q >> 6;  // segment index, uniform per wave
      float p0 = 1.f, p1 = 1.f, p2 = 1.f, p3 = 1.f;
      for (int k = 0; k < j; ++k) {
        p0 *= wtot[2 * k];            // gate0: slot A, waves 0..3
        p1 *= wtot[2 * (4 + k)];      // gate1: slot A, waves 4..7
        p2 *= wtot[2 * k + 1];        // gate2: slot B, waves 0..3
        p3 *= wtot[2 * (4 + k) + 1];  // gate3: slot B, waves 4..7
      }
      float fg = sigm(qv[t] * p0);
      float ig = sigm(qv[256 + t] * p1);
      float gg = tanh_f(qv[512 + t] * p2);
      float og = sigm(qv[768 + t] * p3);
      cx = fg * cx + ig * gg;
      float hv = og * tanh_f(cx);
      // fused sinusoidal PE on downstream h (recurrence uses raw hv)
      float ang = (float)st * pediv;
      float pe = (q & 1) ? __cosf(ang) : __sinf(ang);
      hb[((b << 8) + st) * 256 + q] = hv + pe;
      float nb = __shfl_xor(hv, 1, 64);
      if ((t & 1) == 0) hp[t >> 1] = (unsigned)f2bf(hv) | ((unsigned)f2bf(nb) << 16);
    }
    __syncthreads();  // bar3: hp ready
    xa = xa_n;
    xb = xb_n;
  }
}

// ---------------- qproj x3 fused (f32 out, contiguous q/k/v buffers) ----------------
__global__ void qproj3_kernel(const float* __restrict__ hin, const float* __restrict__ thetas,
                              float* __restrict__ outbase) {
  __shared__ float wtot[4];
  int tok = blockIdx.x, y = blockIdx.y;
  int tid = threadIdx.x, lane = tid & 63, wid = tid >> 6;
  const float* theta = thetas + y * 256;
  float* out = outbase + (long)y * 1048576;
  float v = __cosf(hin[tok * 256 + tid] + theta[tid]);
#pragma unroll
  for (int off = 1; off < 64; off <<= 1) {
    float o = __shfl_up(v, off, 64);
    if (lane >= off) v *= o;
  }
  if (lane == 63) wtot[wid] = v;
  __syncthreads();
  float pre = 1.f;
  for (int w = 0; w < wid; ++w) pre *= wtot[w];
  out[tok * 256 + tid] = v * pre;
}

// ---------------- fused layernorm(h+delta)->h  +  qproj->bf16 (FFN input) ----------------
__global__ void ln_qproj_kernel(float* __restrict__ hio, const float* __restrict__ delta,
                                const float* __restrict__ gamma, const float* __restrict__ beta,
                                const float* __restrict__ theta,
                                unsigned short* __restrict__ outb) {
  __shared__ float red[16];
  __shared__ float wtot[4];
  int tok = blockIdx.x, tid = threadIdx.x, lane = tid & 63, wid = tid >> 6;
  float v = hio[tok * 256 + tid] + delta[tok * 256 + tid];
  float s1 = v, s2 = v * v;
#pragma unroll
  for (int off = 32; off; off >>= 1) {
    s1 += __shfl_xor(s1, off, 64);
    s2 += __shfl_xor(s2, off, 64);
  }
  if (lane == 0) { red[wid] = s1; red[wid + 8] = s2; }
  __syncthreads();
  float t1 = red[0] + red[1] + red[2] + red[3];
  float t2 = red[8] + red[9] + red[10] + red[11];
  float mean = t1 * (1.f / 256.f);
  float var = t2 * (1.f / 256.f) - mean * mean;
  float w = rsqrtf(var + 1e-5f);
  float val = (v - mean) * w * gamma[tid] + beta[tid];
  hio[tok * 256 + tid] = val;
  float c = __cosf(val + theta[tid]);
#pragma unroll
  for (int off = 1; off < 64; off <<= 1) {
    float o = __shfl_up(c, off, 64);
    if (lane >= off) c *= o;
  }
  if (lane == 63) wtot[wid] = c;
  __syncthreads();
  float pre = 1.f;
  for (int k = 0; k < wid; ++k) pre *= wtot[k];
  outb[tok * 256 + tid] = f2bf(c * pre);
}

// ---------------- attention: block per (head,batch); vectorized LDS ----------------
__global__ void __launch_bounds__(256, 1) attn_kernel(const float* __restrict__ qb,
                                                      const float* __restrict__ kb,
                                                      const float* __restrict__ vb,
                                                      unsigned short* __restrict__ outb) {
  extern __shared__ float sm[];
  float* Qs = sm;                 // [256][36]
  float* Ks = Qs + 256 * 36;      // [256][36]
  float* Vs = Ks + 256 * 36;      // [32][260]  d-major
  float* ps = Vs + 32 * 260;      // [4][256]
  int hd = blockIdx.x, b = blockIdx.y;
  int tid = threadIdx.x, lane = tid & 63, wid = tid >> 6;
  const float scale = 0.17677669529663687f;  // 1/sqrt(32)

  for (int i = tid; i < 256 * 32; i += 256) {
    int r = i >> 5, d = i & 31;
    int src = (b * 256 + r) * 256 + hd * 32 + d;
    Qs[r * 36 + d] = qb[src];
    Ks[r * 36 + d] = kb[src];
    Vs[d * 260 + r] = vb[src];
  }
  __syncthreads();

  float* pw = ps + wid * 256;
  for (int r = wid; r < 256; r += 4) {
    float4 qreg[8];
    const float4* qrow = (const float4*)(Qs + r * 36);
#pragma unroll
    for (int i = 0; i < 8; ++i) qreg[i] = qrow[i];
    float s[4];
#pragma unroll
    for (int j = 0; j < 4; ++j) {
      int k = lane + 64 * j;
      const float4* kr = (const float4*)(Ks + k * 36);
      float a = 0.f;
#pragma unroll
      for (int i = 0; i < 8; ++i) {
        float4 kv = kr[i];
        a += qreg[i].x * kv.x + qreg[i].y * kv.y + qreg[i].z * kv.z + qreg[i].w * kv.w;
      }
      s[j] = a * scale;
    }
    float m = fmaxf(fmaxf(s[0], s[1]), fmaxf(s[2], s[3]));
#pragma unroll
    for (int off = 32; off; off >>= 1) m = fmaxf(m, __shfl_xor(m, off, 64));
    float p[4], sum = 0.f;
#pragma unroll
    for (int j = 0; j < 4; ++j) { p[j] = __expf(s[j] - m); sum += p[j]; }
#pragma unroll
    for (int off = 32; off; off >>= 1) sum += __shfl_xor(sum, off, 64);
    float inv = rcp_f(sum);
#pragma unroll
    for (int j = 0; j < 4; ++j) pw[lane + 64 * j] = p[j] * inv;
    int d = lane & 31, half = lane >> 5;
    const float4* pv = (const float4*)(pw + half * 128);
    const float4* v4 = (const float4*)(Vs + d * 260 + half * 128);
    float a = 0.f;
#pragma unroll
    for (int i = 0; i < 32; ++i) {
      float4 pp = pv[i];
      float4 vv = v4[i];
      a += pp.x * vv.x + pp.y * vv.y + pp.z * vv.z + pp.w * vv.w;
    }
    a += __shfl_down(a, 32, 64);
    if (lane < 32) outb[(b * 256 + r) * 256 + hd * 32 + d] = f2bf(a);
  }
}

// ---------------- layernorm(h + delta) -> h ----------------
__global__ void ln_kernel(float* __restrict__ hio, const float* __restrict__ delta,
                          const float* __restrict__ gamma, const float* __restrict__ beta) {
  __shared__ float red[16];
  int tok = blockIdx.x, tid = threadIdx.x, lane = tid & 63, wid = tid >> 6;
  float v = hio[tok * 256 + tid] + delta[tok * 256 + tid];
  float s1 = v, s2 = v * v;
#pragma unroll
  for (int off = 32; off; off >>= 1) {
    s1 += __shfl_xor(s1, off, 64);
    s2 += __shfl_xor(s2, off, 64);
  }
  if (lane == 0) { red[wid] = s1; red[wid + 8] = s2; }
  __syncthreads();
  float t1 = red[0] + red[1] + red[2] + red[3];
  float t2 = red[8] + red[9] + red[10] + red[11];
  float mean = t1 * (1.f / 256.f);
  float var = t2 * (1.f / 256.f) - mean * mean;
  float w = rsqrtf(var + 1e-5f);
  hio[tok * 256 + tid] = (v - mean) * w * gamma[tid] + beta[tid];
}

// ---------------- pool stage A: partial sums over 16-step chunks ----------------
__global__ void poolA_kernel(const float* __restrict__ h, float* __restrict__ partial) {
  int bx = blockIdx.x;  // 0..255
  int b = bx >> 4, ch = bx & 15;
  int tid = threadIdx.x;
  float s = 0.f;
  for (int tt = ch * 16; tt < ch * 16 + 16; ++tt) s += h[((b << 8) + tt) * 256 + tid];
  partial[bx * 256 + tid] = s;
}

// ---------------- pool stage B: reduce + classifier ----------------
__global__ void poolB_kernel(const float* __restrict__ partial, const float* __restrict__ clsW,
                             const float* __restrict__ clsb, float* __restrict__ out) {
  __shared__ float pl[256];
  __shared__ float red[8];
  int b = blockIdx.x, tid = threadIdx.x, lane = tid & 63, wid = tid >> 6;
  float s = 0.f;
  for (int ch = 0; ch < 16; ++ch) s += partial[(b * 16 + ch) * 256 + tid];
  pl[tid] = s * (1.f / 256.f);
  __syncthreads();
  for (int c = 0; c < 4; ++c) {
    float v = pl[tid] * clsW[tid * 4 + c];
#pragma unroll
    for (int off = 32; off; off >>= 1) v += __shfl_xor(v, off, 64);
    if (lane == 0) red[wid] = v;
    __syncthreads();
    if (tid == 0) out[b * 4 + c] = red[0] + red[1] + red[2] + red[3] + clsb[c];
    __syncthreads();
  }
}

extern "C" void kernel_launch(void* const* d_in, const int* in_sizes, int n_in,
                              void* d_out, int out_size, void* d_ws, size_t ws_size,
                              hipStream_t stream) {
  const int* x = (const int*)d_in[0];
  const float* token_emb = (const float*)d_in[1];
  const float* lstm_W = (const float*)d_in[2];
  const float* lstm_b = (const float*)d_in[3];
  const float* lstm_th = (const float*)d_in[4];
  const float* ln1_g = (const float*)d_in[5];
  const float* ln1_b = (const float*)d_in[6];
  const float* ln2_g = (const float*)d_in[7];
  const float* ln2_b = (const float*)d_in[8];
  const float* qkv_th = (const float*)d_in[9];
  const float* comb_W = (const float*)d_in[10];
  const float* comb_b = (const float*)d_in[11];
  const float* ffn_th = (const float*)d_in[12];
  const float* lin1_W = (const float*)d_in[13];
  const float* lin1_b = (const float*)d_in[14];
  const float* lin2_W = (const float*)d_in[15];
  const float* lin2_b = (const float*)d_in[16];
  const float* cls_W = (const float*)d_in[17];
  const float* cls_b = (const float*)d_in[18];

  float* ws = (float*)d_ws;
  typedef unsigned short ushort_t;
  ushort_t* emb_b = (ushort_t*)ws;       // 1M f32 region: emb bf16 pre-loop / attn bf16 in-loop
  ushort_t* att_b = emb_b;
  float* xw = ws + 1048576;              // 4M f32: xw pre-loop / ffh bf16 in-loop
  ushort_t* ffh_b = (ushort_t*)xw;
  float* hb = ws + 5242880;   // 1M
  float* qq = ws + 6291456;   // 1M  (qq,kk,vv contiguous for fused qproj3)
  float* kk = ws + 7340032;   // 1M
  float* vv = ws + 8388608;   // 1M
  float* tmp = ws + 9437184;  // 1M; first 131072 u32 reused pre-loop for lstm weight packs
  unsigned* Wreg = (unsigned*)tmp;            // 98304 uints (gates 0..2 packed)
  unsigned* WLg = (unsigned*)(tmp + 98304);   // 32768 uints (gate 3 packed)
  ushort_t* ffq_b = (ushort_t*)(ws + 10485760);  // 1M ushort
  ushort_t* wxt_b = (ushort_t*)(ws + 11534336);  // 262144 (4 gates x [256][256])
  ushort_t* cmb_b = wxt_b + 262144;              // 2 x 65536
  ushort_t* l1_b = cmb_b + 131072;               // 2 x 262144
  ushort_t* l2_b = l1_b + 524288;                // 2 x 262144
  float* partial = ws + 12255232;                // 256*256 f32 = 256 KB

  const int LSTM_LDS = 131072 + 8192 + 4096 + 64 + 512;            // 143936 B
  const int ATT_LDS = (256 * 36 * 2 + 32 * 260 + 4 * 256) * 4;     // 111104 B
  (void)hipFuncSetAttribute(reinterpret_cast<const void*>(lstm_kernel),
                            hipFuncAttributeMaxDynamicSharedMemorySize, LSTM_LDS);
  (void)hipFuncSetAttribute(reinterpret_cast<const void*>(attn_kernel),
                            hipFuncAttributeMaxDynamicSharedMemorySize, ATT_LDS);

  embed_kernel<<<4096, 256, 0, stream>>>(x, token_emb, emb_b);
  pack_wreg_kernel<<<384, 256, 0, stream>>>(lstm_W, Wreg);
  pack_wl_kernel<<<128, 256, 0, stream>>>(lstm_W, WLg);
  pack_bt<<<dim3(4, 4, 4), 256, 0, stream>>>(lstm_W, 256, 256, wxt_b, 131072, 65536);
  pack_bt<<<dim3(4, 4, 2), 256, 0, stream>>>(comb_W, 256, 256, cmb_b, 65536, 65536);
  pack_bt<<<dim3(16, 4, 2), 256, 0, stream>>>(lin1_W, 256, 1024, l1_b, 262144, 262144);
  pack_bt<<<dim3(4, 16, 2), 256, 0, stream>>>(lin2_W, 1024, 256, l2_b, 262144, 262144);

  // xw = emb @ Wx + lstm_b : M=4096 N=1024 K=256
  gemm_mfma<<<dim3(8, 32), 256, 0, stream>>>(emb_b, wxt_b, lstm_b,
                                             xw, nullptr, 4096, 1024, 256, 0);
  lstm_kernel<<<16, 512, LSTM_LDS, stream>>>(Wreg, WLg, lstm_th, xw, hb);

  for (int l = 0; l < 2; ++l) {
    qproj3_kernel<<<dim3(4096, 3), 256, 0, stream>>>(hb, qkv_th + l * 768, qq);
    attn_kernel<<<dim3(8, 16), 256, ATT_LDS, stream>>>(qq, kk, vv, att_b);
    gemm64<<<dim3(4, 64), 256, 0, stream>>>(att_b, cmb_b + l * 65536, comb_b + l * 256,
                                            tmp, 4096, 256, 256);
    ln_qproj_kernel<<<4096, 256, 0, stream>>>(hb, tmp, ln1_g + l * 256, ln1_b + l * 256,
                                              ffn_th + l * 256, ffq_b);
    gemm_mfma<<<dim3(8, 32), 256, 0, stream>>>(ffq_b, l1_b + l * 262144, lin1_b + l * 1024,
                                               nullptr, ffh_b, 4096, 1024, 256, 1);
    gemm64<<<dim3(4, 64), 256, 0, stream>>>(ffh_b, l2_b + l * 262144, lin2_b + l * 256,
                                            tmp, 4096, 256, 1024);
    ln_kernel<<<4096, 256, 0, stream>>>(hb, tmp, ln2_g + l * 256, ln2_b + l * 256);
  }

  poolA_kernel<<<256, 256, 0, stream>>>(hb, partial);
  poolB_kernel<<<16, 256, 0, stream>>>(partial, cls_W, cls_b, (float*)d_out);
}

// Round 11
// 1308.407 us; speedup vs baseline: 1.1682x; 1.1682x over previous
//
#include <hip/hip_runtime.h>
#include <hip/hip_bf16.h>

// Problem constants: B=16, S=256, V=32000, E=256, H=8, L=2, FFN=1024, NC=4, DK=32, NQ=256

typedef __attribute__((ext_vector_type(8))) short bf8v;   // 8 bf16 in 4 VGPRs
typedef __attribute__((ext_vector_type(4))) float f4v;    // MFMA accumulator
#define MFMA16 __builtin_amdgcn_mfma_f32_16x16x32_bf16

__device__ __forceinline__ unsigned short f2bf(float f) {
  unsigned u = __builtin_bit_cast(unsigned, f);
  u += 0x7fffu + ((u >> 16) & 1u);
  return (unsigned short)(u >> 16);
}
__device__ __forceinline__ float rcp_f(float x) { return __builtin_amdgcn_rcpf(x); }
__device__ __forceinline__ float sigm(float x) { return rcp_f(1.f + __expf(-x)); }
__device__ __forceinline__ float tanh_f(float x) { return 1.f - 2.f * rcp_f(__expf(2.f * x) + 1.f); }

// v_dot2_f32_bf16: acc += a.x*b.x + a.y*b.y  (packed bf16 pairs in uint)
#define DOT2BF(acc, a, b) \
  asm("v_dot2_f32_bf16 %0, %1, %2, %0" : "+v"(acc) : "v"(a), "v"(b))

// ---------------- embedding gather -> bf16 ----------------
__global__ void embed_kernel(const int* __restrict__ x, const float* __restrict__ tab,
                             unsigned short* __restrict__ eb) {
  int tok = blockIdx.x, tid = threadIdx.x;
  eb[tok * 256 + tid] = f2bf(tab[x[tok] * 256 + tid]);
}

// ---- transpose to bf16: W [K][N] f32 -> T[n][k] bf16 ; blockIdx.z batches slices ----
__global__ void pack_bt(const float* __restrict__ W, int K, int N,
                        unsigned short* __restrict__ Th, long wz, long tz) {
  __shared__ float tile[64][65];
  W += (long)blockIdx.z * wz;
  Th += (long)blockIdx.z * tz;
  int n0 = blockIdx.x * 64, k0 = blockIdx.y * 64;
  int tid = threadIdx.x, tx = tid & 63, ty = tid >> 6;
  for (int r = ty; r < 64; r += 4) tile[r][tx] = W[(k0 + r) * N + n0 + tx];
  __syncthreads();
  for (int r = ty; r < 64; r += 4) {
    Th[(n0 + r) * K + k0 + tx] = f2bf(tile[tx][r]);  // = W[k0+tx][n0+r]
  }
}

// ---- pack h-part of gates 0..2 as bf16 d-pairs; half-split (s=0..1, 128 d each) ----
// uint o = ((gs*16 + i4)*256 + q)*4 + c ; gs=gi*2+s, pair i=i4*4+c, d=s*128+2i
__global__ void pack_wreg_kernel(const float* __restrict__ lstmW, unsigned* __restrict__ Wreg) {
  int o = blockIdx.x * 256 + threadIdx.x;  // < 98304
  int c = o & 3;
  int q = (o >> 2) & 255;
  int i4 = (o >> 10) & 15;
  int gs = o >> 14;  // 0..5
  int gi = gs >> 1, s = gs & 1;
  int i = i4 * 4 + c;
  int d = s * 128 + 2 * i;
  unsigned lo = f2bf(lstmW[(gi * 512 + 256 + d) * 256 + q]);
  unsigned hi = f2bf(lstmW[(gi * 512 + 256 + d + 1) * 256 + q]);
  Wreg[o] = lo | (hi << 16);
}

// ---- pack h-part of gate 3 as bf16 d-pairs for LDS ----
__global__ void pack_wl_kernel(const float* __restrict__ lstmW, unsigned* __restrict__ WLg) {
  int o = blockIdx.x * 256 + threadIdx.x;  // < 32768
  int c = o & 3;
  int q = (o >> 2) & 255;
  int p4 = o >> 10;  // 0..31
  int d = 2 * (p4 * 4 + c);
  unsigned lo = f2bf(lstmW[(3 * 512 + 256 + d) * 256 + q]);
  unsigned hi = f2bf(lstmW[(3 * 512 + 256 + d + 1) * 256 + q]);
  WLg[o] = lo | (hi << 16);
}

// ---------------- MFMA GEMM 128x128: C = A*B + bias ----------------
__global__ void __launch_bounds__(256) gemm_mfma(const unsigned short* __restrict__ A,
                                                 const unsigned short* __restrict__ B,
                                                 const float* __restrict__ bias,
                                                 float* __restrict__ Cf,
                                                 unsigned short* __restrict__ Cb,
                                                 int M, int N, int K, int mode) {
  __shared__ unsigned short As[128 * 40];
  __shared__ unsigned short Bs[128 * 40];

  const int tid = threadIdx.x;
  const int lane = tid & 63;
  const int wid = tid >> 6;
  const int wr = wid >> 1, wc = wid & 1;
  const int bm = blockIdx.y * 128, bn = blockIdx.x * 128;

  const int srow = tid >> 2;
  const int scol = (tid & 3) * 8;

  f4v acc[4][4] = {};

  for (int kt = 0; kt < K; kt += 32) {
#pragma unroll
    for (int p = 0; p < 2; ++p) {
      int r = srow + p * 64;
      *(uint4*)(&As[r * 40 + scol]) = *(const uint4*)(&A[(bm + r) * K + kt + scol]);
      *(uint4*)(&Bs[r * 40 + scol]) = *(const uint4*)(&B[(bn + r) * K + kt + scol]);
    }
    __syncthreads();

    bf8v a[4], b[4];
    const int kq = (lane >> 4) * 8;
#pragma unroll
    for (int f = 0; f < 4; ++f) {
      a[f] = *(const bf8v*)(&As[(wr * 64 + f * 16 + (lane & 15)) * 40 + kq]);
      b[f] = *(const bf8v*)(&Bs[(wc * 64 + f * 16 + (lane & 15)) * 40 + kq]);
    }
#pragma unroll
    for (int fm = 0; fm < 4; ++fm)
#pragma unroll
      for (int fn = 0; fn < 4; ++fn)
        acc[fm][fn] = MFMA16(a[fm], b[fn], acc[fm][fn], 0, 0, 0);
    __syncthreads();
  }

#pragma unroll
  for (int fm = 0; fm < 4; ++fm)
#pragma unroll
    for (int fn = 0; fn < 4; ++fn) {
      int c = bn + wc * 64 + fn * 16 + (lane & 15);
      int r0 = bm + wr * 64 + fm * 16 + ((lane >> 4) << 2);
      float bv = bias[c];
#pragma unroll
      for (int j = 0; j < 4; ++j) {
        float v = acc[fm][fn][j] + bv;
        if (mode == 1) {
          Cb[(r0 + j) * N + c] = f2bf(fmaxf(v, 0.f));
        } else {
          Cf[(r0 + j) * N + c] = v;
        }
      }
    }
}

// ---------------- MFMA GEMM 64x64 tile (for N=256: 4x the blocks of 128-tile) ----------------
__global__ void __launch_bounds__(256) gemm64(const unsigned short* __restrict__ A,
                                              const unsigned short* __restrict__ B,
                                              const float* __restrict__ bias,
                                              float* __restrict__ Cf,
                                              int M, int N, int K) {
  __shared__ unsigned short As[64 * 40];
  __shared__ unsigned short Bs[64 * 40];

  const int tid = threadIdx.x;
  const int lane = tid & 63;
  const int wid = tid >> 6;          // wave owns M-rows [wid*16, wid*16+16)
  const int bm = blockIdx.y * 64, bn = blockIdx.x * 64;
  const int srow = tid >> 2;         // 0..63
  const int scol = (tid & 3) * 8;

  f4v acc[4] = {};

  for (int kt = 0; kt < K; kt += 32) {
    *(uint4*)(&As[srow * 40 + scol]) = *(const uint4*)(&A[(bm + srow) * K + kt + scol]);
    *(uint4*)(&Bs[srow * 40 + scol]) = *(const uint4*)(&B[(bn + srow) * K + kt + scol]);
    __syncthreads();

    const int kq = (lane >> 4) * 8;
    bf8v a = *(const bf8v*)(&As[(wid * 16 + (lane & 15)) * 40 + kq]);
#pragma unroll
    for (int f = 0; f < 4; ++f) {
      bf8v b = *(const bf8v*)(&Bs[(f * 16 + (lane & 15)) * 40 + kq]);
      acc[f] = MFMA16(a, b, acc[f], 0, 0, 0);
    }
    __syncthreads();
  }

#pragma unroll
  for (int f = 0; f < 4; ++f) {
    int c = bn + f * 16 + (lane & 15);
    int r0 = bm + wid * 16 + ((lane >> 4) << 2);
    float bv = bias[c];
#pragma unroll
    for (int j = 0; j < 4; ++j) {
      Cf[(r0 + j) * N + c] = acc[f][j] + bv;
    }
  }
}

// ---------------- QLSTM: one block per batch; 512 threads; half d-split -------------
// REVERT to the best-measured structure (605 us): gates 0..2 half-columns in uint4
// wreg[48] (L2-resident reloads at ~2.4 us/step = per-CU L2 BW floor), gate 3 in LDS.
// PLUS: sinusoidal PE fused into the downstream h write (recurrence uses raw hv).
__global__ void __launch_bounds__(512)
__attribute__((amdgpu_waves_per_eu(2, 2)))
lstm_kernel(const unsigned* __restrict__ Wreg,
            const unsigned* __restrict__ WLg,
            const float* __restrict__ lstmTh,
            const float* __restrict__ xw,
            float* __restrict__ hb) {
  extern __shared__ char smem[];
  unsigned* WL = (unsigned*)smem;               // [32][256] uint4 rows (131072 B)
  float* part = (float*)(smem + 131072);        // [8][256]  (g*2+s, q)
  float* qv = part + 2048;                      // [1024]
  float* wtot = qv + 1024;                      // [16]  (wave, slot)
  unsigned* hp = (unsigned*)(wtot + 16);        // [128] packed bf16 h pairs

  const int t = threadIdx.x;
  const int b = blockIdx.x;
  const int q = t & 255;
  const int s = t >> 8;          // d-half: d in [s*128, s*128+128)
  const int lane = t & 63;
  const int w = t >> 6;          // wave 0..7

  {
    const uint4* src = (const uint4*)WLg;
    uint4* dst = (uint4*)WL;
    for (int j = t; j < 8192; j += 512) dst[j] = src[j];
  }
  const uint4* Wreg4 = (const uint4*)Wreg;
  uint4 wreg[48];
#pragma unroll
  for (int j = 0; j < 48; ++j) {
    int gi = j >> 4, i4 = j & 15;
    wreg[j] = Wreg4[((gi * 2 + s) * 16 + i4) * 256 + q];
  }
  const float thA = lstmTh[t];          // gate s, col q
  const float thB = lstmTh[512 + t];    // gate s+2, col q
  float cx = 0.f;                       // valid for t<256 (q-owner)
  if (t < 128) hp[t] = 0u;
  __syncthreads();

  const int xbase = (b << 8) * 1024;
  const uint4* WL4 = (const uint4*)WL;
  const uint4* hp4 = (const uint4*)hp;
  // PE constants for this thread's output column q (used when t<256)
  const float pediv = __expf((float)(q >> 1) * -0.07195578415622253f);

  for (int st = 0; st < 256; ++st) {
    // xw loads issued early; consumed after bar1 (latency hidden under GEMV)
    float xa = xw[xbase + st * 1024 + t];
    float xb = xw[xbase + st * 1024 + 512 + t];

    // ---- GEMV half-dots: 4 gates, 128 d each (64 packed pairs = 16 uint4) ----
    float a0 = 0.f, a1 = 0.f, a2 = 0.f, a3 = 0.f;
#pragma unroll
    for (int i4 = 0; i4 < 16; ++i4) {
      uint4 hh = hp4[(s << 4) + i4];                 // broadcast b128
      uint4 w3 = WL4[((s << 4) + i4) * 256 + q];     // sequential b128
      uint4 w0 = wreg[i4];
      uint4 w1 = wreg[16 + i4];
      uint4 w2 = wreg[32 + i4];
      DOT2BF(a0, w0.x, hh.x); DOT2BF(a0, w0.y, hh.y);
      DOT2BF(a0, w0.z, hh.z); DOT2BF(a0, w0.w, hh.w);
      DOT2BF(a1, w1.x, hh.x); DOT2BF(a1, w1.y, hh.y);
      DOT2BF(a1, w1.z, hh.z); DOT2BF(a1, w1.w, hh.w);
      DOT2BF(a2, w2.x, hh.x); DOT2BF(a2, w2.y, hh.y);
      DOT2BF(a2, w2.z, hh.z); DOT2BF(a2, w2.w, hh.w);
      DOT2BF(a3, w3.x, hh.x); DOT2BF(a3, w3.y, hh.y);
      DOT2BF(a3, w3.z, hh.z); DOT2BF(a3, w3.w, hh.w);
    }
    part[(0 * 2 + s) * 256 + q] = a0;
    part[(1 * 2 + s) * 256 + q] = a1;
    part[(2 * 2 + s) * 256 + q] = a2;
    part[(3 * 2 + s) * 256 + q] = a3;
    __syncthreads();  // bar1: partials ready

    // ---- finalize z, cos; cumprod scan along q (4 waves per gate, 2 slots) ----
    int gA = s, gB = s + 2;
    float zA = part[(gA * 2 + 0) * 256 + q] + part[(gA * 2 + 1) * 256 + q] + xa + thA;
    float zB = part[(gB * 2 + 0) * 256 + q] + part[(gB * 2 + 1) * 256 + q] + xb + thB;
    float vA = __cosf(zA);
    float vB = __cosf(zB);
#pragma unroll
    for (int off = 1; off < 64; off <<= 1) {
      float oA = __shfl_up(vA, off, 64);
      float oB = __shfl_up(vB, off, 64);
      if (lane >= off) { vA *= oA; vB *= oB; }
    }
    if (lane == 63) { wtot[w * 2] = vA; wtot[w * 2 + 1] = vB; }
    __syncthreads();  // bar2: wtot ready
    {
      float pA = 1.f, pB = 1.f;
      int w0 = w & ~3;
      for (int k = w0; k < w; ++k) { pA *= wtot[k * 2]; pB *= wtot[k * 2 + 1]; }
      vA *= pA;
      vB *= pB;
    }
    qv[t] = vA;        // gate s,   col q
    qv[512 + t] = vB;  // gate s+2, col q
    __syncthreads();  // bar3: qv ready

    // ---- combine gates, update cx/h (threads 0..255 own q) ----
    if (t < 256) {
      float fg = sigm(qv[t]);
      float ig = sigm(qv[256 + t]);
      float gg = tanh_f(qv[512 + t]);
      float og = sigm(qv[768 + t]);
      cx = fg * cx + ig * gg;
      float hv = og * tanh_f(cx);
      // fused sinusoidal PE for the downstream h (recurrence uses raw hv via hp)
      float ang = (float)st * pediv;
      float pe = (q & 1) ? __cosf(ang) : __sinf(ang);
      hb[((b << 8) + st) * 256 + q] = hv + pe;
      float nb = __shfl_xor(hv, 1, 64);
      if ((t & 1) == 0) hp[t >> 1] = (unsigned)f2bf(hv) | ((unsigned)f2bf(nb) << 16);
    }
    __syncthreads();  // bar4: hp ready
  }
}

// ---------------- qproj x3 fused (f32 out, contiguous q/k/v buffers) ----------------
__global__ void qproj3_kernel(const float* __restrict__ hin, const float* __restrict__ thetas,
                              float* __restrict__ outbase) {
  __shared__ float wtot[4];
  int tok = blockIdx.x, y = blockIdx.y;
  int tid = threadIdx.x, lane = tid & 63, wid = tid >> 6;
  const float* theta = thetas + y * 256;
  float* out = outbase + (long)y * 1048576;
  float v = __cosf(hin[tok * 256 + tid] + theta[tid]);
#pragma unroll
  for (int off = 1; off < 64; off <<= 1) {
    float o = __shfl_up(v, off, 64);
    if (lane >= off) v *= o;
  }
  if (lane == 63) wtot[wid] = v;
  __syncthreads();
  float pre = 1.f;
  for (int w = 0; w < wid; ++w) pre *= wtot[w];
  out[tok * 256 + tid] = v * pre;
}

// ---------------- fused layernorm(h+delta)->h  +  qproj->bf16 (FFN input) ----------------
__global__ void ln_qproj_kernel(float* __restrict__ hio, const float* __restrict__ delta,
                                const float* __restrict__ gamma, const float* __restrict__ beta,
                                const float* __restrict__ theta,
                                unsigned short* __restrict__ outb) {
  __shared__ float red[16];
  __shared__ float wtot[4];
  int tok = blockIdx.x, tid = threadIdx.x, lane = tid & 63, wid = tid >> 6;
  float v = hio[tok * 256 + tid] + delta[tok * 256 + tid];
  float s1 = v, s2 = v * v;
#pragma unroll
  for (int off = 32; off; off >>= 1) {
    s1 += __shfl_xor(s1, off, 64);
    s2 += __shfl_xor(s2, off, 64);
  }
  if (lane == 0) { red[wid] = s1; red[wid + 8] = s2; }
  __syncthreads();
  float t1 = red[0] + red[1] + red[2] + red[3];
  float t2 = red[8] + red[9] + red[10] + red[11];
  float mean = t1 * (1.f / 256.f);
  float var = t2 * (1.f / 256.f) - mean * mean;
  float w = rsqrtf(var + 1e-5f);
  float val = (v - mean) * w * gamma[tid] + beta[tid];
  hio[tok * 256 + tid] = val;
  float c = __cosf(val + theta[tid]);
#pragma unroll
  for (int off = 1; off < 64; off <<= 1) {
    float o = __shfl_up(c, off, 64);
    if (lane >= off) c *= o;
  }
  if (lane == 63) wtot[wid] = c;
  __syncthreads();
  float pre = 1.f;
  for (int k = 0; k < wid; ++k) pre *= wtot[k];
  outb[tok * 256 + tid] = f2bf(c * pre);
}

// ---------------- attention: block per (head,batch); K/V in LDS, Q from global ----------
// LDS 74 KB -> 2 blocks/CU. Q rows are wave-uniform -> global loads broadcast via L1.
__global__ void __launch_bounds__(256) attn_kernel(const float* __restrict__ qb,
                                                   const float* __restrict__ kb,
                                                   const float* __restrict__ vb,
                                                   unsigned short* __restrict__ outb) {
  extern __shared__ float sm[];
  float* Ks = sm;                 // [256][36]
  float* Vs = Ks + 256 * 36;      // [32][260]  d-major
  float* ps = Vs + 32 * 260;      // [4][256]
  int hd = blockIdx.x, b = blockIdx.y;
  int tid = threadIdx.x, lane = tid & 63, wid = tid >> 6;
  const float scale = 0.17677669529663687f;  // 1/sqrt(32)

  for (int i = tid; i < 256 * 32; i += 256) {
    int r = i >> 5, d = i & 31;
    int src = (b * 256 + r) * 256 + hd * 32 + d;
    Ks[r * 36 + d] = kb[src];
    Vs[d * 260 + r] = vb[src];
  }
  __syncthreads();

  float* pw = ps + wid * 256;
  for (int r = wid; r < 256; r += 4) {
    // q row: wave-uniform global load (L1 broadcast), 8 x float4
    const float4* qrow = (const float4*)(qb + (b * 256 + r) * 256 + hd * 32);
    float4 qreg[8];
#pragma unroll
    for (int i = 0; i < 8; ++i) qreg[i] = qrow[i];
    float s[4];
#pragma unroll
    for (int j = 0; j < 4; ++j) {
      int k = lane + 64 * j;
      const float4* kr = (const float4*)(Ks + k * 36);
      float a = 0.f;
#pragma unroll
      for (int i = 0; i < 8; ++i) {
        float4 kv = kr[i];
        a += qreg[i].x * kv.x + qreg[i].y * kv.y + qreg[i].z * kv.z + qreg[i].w * kv.w;
      }
      s[j] = a * scale;
    }
    float m = fmaxf(fmaxf(s[0], s[1]), fmaxf(s[2], s[3]));
#pragma unroll
    for (int off = 32; off; off >>= 1) m = fmaxf(m, __shfl_xor(m, off, 64));
    float p[4], sum = 0.f;
#pragma unroll
    for (int j = 0; j < 4; ++j) { p[j] = __expf(s[j] - m); sum += p[j]; }
#pragma unroll
    for (int off = 32; off; off >>= 1) sum += __shfl_xor(sum, off, 64);
    float inv = rcp_f(sum);
#pragma unroll
    for (int j = 0; j < 4; ++j) pw[lane + 64 * j] = p[j] * inv;
    int d = lane & 31, half = lane >> 5;
    const float4* pv = (const float4*)(pw + half * 128);
    const float4* v4 = (const float4*)(Vs + d * 260 + half * 128);
    float a = 0.f;
#pragma unroll
    for (int i = 0; i < 32; ++i) {
      float4 pp = pv[i];
      float4 vv = v4[i];
      a += pp.x * vv.x + pp.y * vv.y + pp.z * vv.z + pp.w * vv.w;
    }
    a += __shfl_down(a, 32, 64);
    if (lane < 32) outb[(b * 256 + r) * 256 + hd * 32 + d] = f2bf(a);
  }
}

// ---------------- layernorm(h + delta) -> h ----------------
__global__ void ln_kernel(float* __restrict__ hio, const float* __restrict__ delta,
                          const float* __restrict__ gamma, const float* __restrict__ beta) {
  __shared__ float red[16];
  int tok = blockIdx.x, tid = threadIdx.x, lane = tid & 63, wid = tid >> 6;
  float v = hio[tok * 256 + tid] + delta[tok * 256 + tid];
  float s1 = v, s2 = v * v;
#pragma unroll
  for (int off = 32; off; off >>= 1) {
    s1 += __shfl_xor(s1, off, 64);
    s2 += __shfl_xor(s2, off, 64);
  }
  if (lane == 0) { red[wid] = s1; red[wid + 8] = s2; }
  __syncthreads();
  float t1 = red[0] + red[1] + red[2] + red[3];
  float t2 = red[8] + red[9] + red[10] + red[11];
  float mean = t1 * (1.f / 256.f);
  float var = t2 * (1.f / 256.f) - mean * mean;
  float w = rsqrtf(var + 1e-5f);
  hio[tok * 256 + tid] = (v - mean) * w * gamma[tid] + beta[tid];
}

// ---------------- final layernorm fused with pool partials (16 tokens per block) -------
__global__ void ln_pool_kernel(float* __restrict__ hio, const float* __restrict__ delta,
                               const float* __restrict__ gamma, const float* __restrict__ beta,
                               float* __restrict__ partial) {
  __shared__ float red[16];
  int bx = blockIdx.x;           // 0..255 : b*16 + chunk
  int b = bx >> 4, ch = bx & 15;
  int tid = threadIdx.x, lane = tid & 63, wid = tid >> 6;
  float g = gamma[tid], be = beta[tid];
  float acc = 0.f;
  for (int k = 0; k < 16; ++k) {
    int tok = (b << 8) + ch * 16 + k;
    float v = hio[tok * 256 + tid] + delta[tok * 256 + tid];
    float s1 = v, s2 = v * v;
#pragma unroll
    for (int off = 32; off; off >>= 1) {
      s1 += __shfl_xor(s1, off, 64);
      s2 += __shfl_xor(s2, off, 64);
    }
    if (lane == 0) { red[wid] = s1; red[wid + 8] = s2; }
    __syncthreads();
    float t1 = red[0] + red[1] + red[2] + red[3];
    float t2 = red[8] + red[9] + red[10] + red[11];
    float mean = t1 * (1.f / 256.f);
    float var = t2 * (1.f / 256.f) - mean * mean;
    float w = rsqrtf(var + 1e-5f);
    float val = (v - mean) * w * g + be;
    hio[tok * 256 + tid] = val;
    acc += val;
    __syncthreads();  // protect red[] before next token
  }
  partial[bx * 256 + tid] = acc;
}

// ---------------- pool stage B: reduce + classifier ----------------
__global__ void poolB_kernel(const float* __restrict__ partial, const float* __restrict__ clsW,
                             const float* __restrict__ clsb, float* __restrict__ out) {
  __shared__ float pl[256];
  __shared__ float red[8];
  int b = blockIdx.x, tid = threadIdx.x, lane = tid & 63, wid = tid >> 6;
  float s = 0.f;
  for (int ch = 0; ch < 16; ++ch) s += partial[(b * 16 + ch) * 256 + tid];
  pl[tid] = s * (1.f / 256.f);
  __syncthreads();
  for (int c = 0; c < 4; ++c) {
    float v = pl[tid] * clsW[tid * 4 + c];
#pragma unroll
    for (int off = 32; off; off >>= 1) v += __shfl_xor(v, off, 64);
    if (lane == 0) red[wid] = v;
    __syncthreads();
    if (tid == 0) out[b * 4 + c] = red[0] + red[1] + red[2] + red[3] + clsb[c];
    __syncthreads();
  }
}

extern "C" void kernel_launch(void* const* d_in, const int* in_sizes, int n_in,
                              void* d_out, int out_size, void* d_ws, size_t ws_size,
                              hipStream_t stream) {
  const int* x = (const int*)d_in[0];
  const float* token_emb = (const float*)d_in[1];
  const float* lstm_W = (const float*)d_in[2];
  const float* lstm_b = (const float*)d_in[3];
  const float* lstm_th = (const float*)d_in[4];
  const float* ln1_g = (const float*)d_in[5];
  const float* ln1_b = (const float*)d_in[6];
  const float* ln2_g = (const float*)d_in[7];
  const float* ln2_b = (const float*)d_in[8];
  const float* qkv_th = (const float*)d_in[9];
  const float* comb_W = (const float*)d_in[10];
  const float* comb_b = (const float*)d_in[11];
  const float* ffn_th = (const float*)d_in[12];
  const float* lin1_W = (const float*)d_in[13];
  const float* lin1_b = (const float*)d_in[14];
  const float* lin2_W = (const float*)d_in[15];
  const float* lin2_b = (const float*)d_in[16];
  const float* cls_W = (const float*)d_in[17];
  const float* cls_b = (const float*)d_in[18];

  float* ws = (float*)d_ws;
  typedef unsigned short ushort_t;
  ushort_t* emb_b = (ushort_t*)ws;       // 1M f32 region: emb bf16 pre-loop / attn bf16 in-loop
  ushort_t* att_b = emb_b;
  float* xw = ws + 1048576;              // 4M f32: xw pre-loop / ffh bf16 in-loop
  ushort_t* ffh_b = (ushort_t*)xw;
  float* hb = ws + 5242880;   // 1M
  float* qq = ws + 6291456;   // 1M  (qq,kk,vv contiguous for fused qproj3)
  float* kk = ws + 7340032;   // 1M
  float* vv = ws + 8388608;   // 1M
  float* tmp = ws + 9437184;  // 1M; first 131072 u32 reused pre-loop for lstm weight packs
  unsigned* Wreg = (unsigned*)tmp;            // 98304 uints (gates 0..2 packed)
  unsigned* WLg = (unsigned*)(tmp + 98304);   // 32768 uints (gate 3 packed)
  ushort_t* ffq_b = (ushort_t*)(ws + 10485760);  // 1M ushort
  ushort_t* wxt_b = (ushort_t*)(ws + 11534336);  // 262144 (4 gates x [256][256])
  ushort_t* cmb_b = wxt_b + 262144;              // 2 x 65536
  ushort_t* l1_b = cmb_b + 131072;               // 2 x 262144
  ushort_t* l2_b = l1_b + 524288;                // 2 x 262144
  float* partial = ws + 12255232;                // 256*256 f32 = 256 KB

  const int LSTM_LDS = 131072 + 8192 + 4096 + 64 + 512;        // 143936 B
  const int ATT_LDS = (256 * 36 + 32 * 260 + 4 * 256) * 4;     // 74240 B
  (void)hipFuncSetAttribute(reinterpret_cast<const void*>(lstm_kernel),
                            hipFuncAttributeMaxDynamicSharedMemorySize, LSTM_LDS);
  (void)hipFuncSetAttribute(reinterpret_cast<const void*>(attn_kernel),
                            hipFuncAttributeMaxDynamicSharedMemorySize, ATT_LDS);

  embed_kernel<<<4096, 256, 0, stream>>>(x, token_emb, emb_b);
  pack_wreg_kernel<<<384, 256, 0, stream>>>(lstm_W, Wreg);
  pack_wl_kernel<<<128, 256, 0, stream>>>(lstm_W, WLg);
  pack_bt<<<dim3(4, 4, 4), 256, 0, stream>>>(lstm_W, 256, 256, wxt_b, 131072, 65536);
  pack_bt<<<dim3(4, 4, 2), 256, 0, stream>>>(comb_W, 256, 256, cmb_b, 65536, 65536);
  pack_bt<<<dim3(16, 4, 2), 256, 0, stream>>>(lin1_W, 256, 1024, l1_b, 262144, 262144);
  pack_bt<<<dim3(4, 16, 2), 256, 0, stream>>>(lin2_W, 1024, 256, l2_b, 262144, 262144);

  // xw = emb @ Wx + lstm_b : M=4096 N=1024 K=256
  gemm_mfma<<<dim3(8, 32), 256, 0, stream>>>(emb_b, wxt_b, lstm_b,
                                             xw, nullptr, 4096, 1024, 256, 0);
  lstm_kernel<<<16, 512, LSTM_LDS, stream>>>(Wreg, WLg, lstm_th, xw, hb);

  for (int l = 0; l < 2; ++l) {
    qproj3_kernel<<<dim3(4096, 3), 256, 0, stream>>>(hb, qkv_th + l * 768, qq);
    attn_kernel<<<dim3(8, 16), 256, ATT_LDS, stream>>>(qq, kk, vv, att_b);
    gemm64<<<dim3(4, 64), 256, 0, stream>>>(att_b, cmb_b + l * 65536, comb_b + l * 256,
                                            tmp, 4096, 256, 256);
    ln_qproj_kernel<<<4096, 256, 0, stream>>>(hb, tmp, ln1_g + l * 256, ln1_b + l * 256,
                                              ffn_th + l * 256, ffq_b);
    gemm_mfma<<<dim3(8, 32), 256, 0, stream>>>(ffq_b, l1_b + l * 262144, lin1_b + l * 1024,
                                               nullptr, ffh_b, 4096, 1024, 256, 1);
    gemm64<<<dim3(4, 64), 256, 0, stream>>>(ffh_b, l2_b + l * 262144, lin2_b + l * 256,
                                            tmp, 4096, 256, 1024);
    if (l == 0) {
      ln_kernel<<<4096, 256, 0, stream>>>(hb, tmp, ln2_g + l * 256, ln2_b + l * 256);
    } else {
      ln_pool_kernel<<<256, 256, 0, stream>>>(hb, tmp, ln2_g + l * 256, ln2_b + l * 256,
                                              partial);
    }
  }

  poolB_kernel<<<16, 256, 0, stream>>>(partial, cls_W, cls_b, (float*)d_out);
}